// Round 1
// baseline (408.494 us; speedup 1.0000x reference)
//
#include <hip/hip_runtime.h>

// SNN layer: out[b,n] = clip( sum_m pre[b,m]*W[m,n] + const[b,n] - thr[b,n], 0, 0.9 )
// B=8, M=8192, N=8192, all fp32. Memory-bound on the single pass over W (268 MB).
//
// Layout: grid = N/32 = 256 blocks (1 per CU), 256 threads/block.
//   tx = tid&7  -> 4 consecutive columns each (float4), 32 cols per block
//   ty = tid>>3 -> 32 K-slices of 256 rows each
// Each thread accumulates acc[8 batches][4 cols]; slices reduced through LDS;
// epilogue (const - thr, clip) fused.

constexpr int Mdim = 8192;
constexpr int Ndim = 8192;
constexpr int Bdim = 8;
constexpr int KSLICES = 32;               // ty count
constexpr int KROWS = Mdim / KSLICES;     // 256 rows per slice

__global__ __launch_bounds__(256, 1) void snn_fused(
    const float* __restrict__ pre,   // [B, M]
    const float* __restrict__ W,     // [M, N]
    const float* __restrict__ thr,   // [B, N]
    const float* __restrict__ cst,   // [B, N]
    float* __restrict__ out)         // [B, N]
{
    __shared__ float partial[KSLICES * Bdim * 32];   // 32 KB

    const int tid = threadIdx.x;
    const int tx  = tid & 7;
    const int ty  = tid >> 3;
    const int colBase = blockIdx.x * 32;
    const int col = colBase + tx * 4;
    const int m0  = ty * KROWS;

    float acc[Bdim][4];
#pragma unroll
    for (int b = 0; b < Bdim; ++b)
#pragma unroll
        for (int c = 0; c < 4; ++c) acc[b][c] = 0.0f;

    // Main loop: 4 rows per iteration. 4 W float4 loads (coalesced 128B per
    // tx-group) + 8 pre float4 loads (same addr across tx lanes -> broadcast).
#pragma unroll 2
    for (int m = m0; m < m0 + KROWS; m += 4) {
        float4 p[Bdim];
#pragma unroll
        for (int b = 0; b < Bdim; ++b)
            p[b] = *reinterpret_cast<const float4*>(pre + b * Mdim + m);

        float4 w0 = *reinterpret_cast<const float4*>(W + (size_t)(m + 0) * Ndim + col);
        float4 w1 = *reinterpret_cast<const float4*>(W + (size_t)(m + 1) * Ndim + col);
        float4 w2 = *reinterpret_cast<const float4*>(W + (size_t)(m + 2) * Ndim + col);
        float4 w3 = *reinterpret_cast<const float4*>(W + (size_t)(m + 3) * Ndim + col);

#pragma unroll
        for (int b = 0; b < Bdim; ++b) {
            acc[b][0] = fmaf(p[b].x, w0.x, acc[b][0]);
            acc[b][1] = fmaf(p[b].x, w0.y, acc[b][1]);
            acc[b][2] = fmaf(p[b].x, w0.z, acc[b][2]);
            acc[b][3] = fmaf(p[b].x, w0.w, acc[b][3]);

            acc[b][0] = fmaf(p[b].y, w1.x, acc[b][0]);
            acc[b][1] = fmaf(p[b].y, w1.y, acc[b][1]);
            acc[b][2] = fmaf(p[b].y, w1.z, acc[b][2]);
            acc[b][3] = fmaf(p[b].y, w1.w, acc[b][3]);

            acc[b][0] = fmaf(p[b].z, w2.x, acc[b][0]);
            acc[b][1] = fmaf(p[b].z, w2.y, acc[b][1]);
            acc[b][2] = fmaf(p[b].z, w2.z, acc[b][2]);
            acc[b][3] = fmaf(p[b].z, w2.w, acc[b][3]);

            acc[b][0] = fmaf(p[b].w, w3.x, acc[b][0]);
            acc[b][1] = fmaf(p[b].w, w3.y, acc[b][1]);
            acc[b][2] = fmaf(p[b].w, w3.z, acc[b][2]);
            acc[b][3] = fmaf(p[b].w, w3.w, acc[b][3]);
        }
    }

    // Dump per-slice partials to LDS: layout [ty][b][col32]
#pragma unroll
    for (int b = 0; b < Bdim; ++b) {
        float4* dst = reinterpret_cast<float4*>(&partial[(ty * Bdim + b) * 32 + tx * 4]);
        *dst = make_float4(acc[b][0], acc[b][1], acc[b][2], acc[b][3]);
    }
    __syncthreads();

    // Reduce across the 32 K-slices: thread -> one (batch, col) output.
    const int ob = tid >> 5;   // batch 0..7
    const int oc = tid & 31;   // col within tile
    float s = 0.0f;
#pragma unroll
    for (int t = 0; t < KSLICES; ++t)
        s += partial[(t * Bdim + ob) * 32 + oc];   // 2 lanes/bank -> conflict-free

    const int oi = ob * Ndim + colBase + oc;
    float x = s + cst[oi] - thr[oi];
    x = fminf(fmaxf(x, 0.0f), 0.9f);
    out[oi] = x;
}

extern "C" void kernel_launch(void* const* d_in, const int* in_sizes, int n_in,
                              void* d_out, int out_size, void* d_ws, size_t ws_size,
                              hipStream_t stream) {
    const float* pre = (const float*)d_in[0];   // [8,1,8192]
    const float* W   = (const float*)d_in[1];   // [8192,8192]
    const float* thr = (const float*)d_in[2];   // [8,1,8192]
    const float* cst = (const float*)d_in[3];   // [8,1,8192]
    float* out = (float*)d_out;                 // [8,1,8192]

    dim3 grid(Ndim / 32);
    dim3 block(256);
    hipLaunchKernelGGL(snn_fused, grid, block, 0, stream, pre, W, thr, cst, out);
}

// Round 2
// 379.012 us; speedup vs baseline: 1.0778x; 1.0778x over previous
//
#include <hip/hip_runtime.h>

// SNN layer: out[b,n] = clip( sum_m pre[b,m]*W[m,n] + cst[b,n] - thr[b,n], 0, 0.9 )
// B=8, M=8192, N=8192 fp32. Memory-bound on one pass over W (268 MB, floor ~43us).
//
// Two-stage split-K:
//  Stage 1: grid (8 col-tiles x 64 K-chunks) = 512 blocks, 256 thr.
//    Block tile = 1024 cols (thread = float4) x 128 rows. Every wave reads
//    1 KB contiguous per row (vs 128 B scattered in R0) -> DRAM-friendly.
//    2 blocks/CU = 8 waves/CU for latency hiding. Partials -> ws (16 MB).
//  Stage 2: sum 64 partials per output + fused (cst - thr, clip) epilogue.

constexpr int Mdim = 8192;
constexpr int Ndim = 8192;
constexpr int Bdim = 8;
constexpr int KCH  = 64;               // K chunks across blocks
constexpr int ROWS = Mdim / KCH;       // 128 rows per stage-1 block
constexpr int TILE_N = 1024;           // cols per stage-1 block
constexpr float CAP = 0.9f;

__global__ __launch_bounds__(256, 2) void snn_stage1(
    const float* __restrict__ pre,   // [B, M]
    const float* __restrict__ W,     // [M, N]
    float* __restrict__ part)        // [KCH, B, N]
{
    const int t   = threadIdx.x;
    const int col = blockIdx.x * TILE_N + t * 4;
    const int r0  = blockIdx.y * ROWS;

    float4 acc[Bdim];
#pragma unroll
    for (int b = 0; b < Bdim; ++b) acc[b] = make_float4(0.f, 0.f, 0.f, 0.f);

    for (int r = r0; r < r0 + ROWS; r += 8) {
        // 8 rows of W: 8 independent dwordx4 loads (8 KB in flight per wave)
        float4 w[8];
#pragma unroll
        for (int j = 0; j < 8; ++j)
            w[j] = *reinterpret_cast<const float4*>(W + (size_t)(r + j) * Ndim + col);

        // pre-spike slices for 8 batches x 8 rows (uniform address -> L1 broadcast)
        float4 pA[Bdim], pB[Bdim];
#pragma unroll
        for (int b = 0; b < Bdim; ++b) {
            pA[b] = *reinterpret_cast<const float4*>(pre + b * Mdim + r);
            pB[b] = *reinterpret_cast<const float4*>(pre + b * Mdim + r + 4);
        }

#pragma unroll
        for (int b = 0; b < Bdim; ++b) {
            float4 a = acc[b];
            a.x = fmaf(pA[b].x, w[0].x, a.x); a.y = fmaf(pA[b].x, w[0].y, a.y);
            a.z = fmaf(pA[b].x, w[0].z, a.z); a.w = fmaf(pA[b].x, w[0].w, a.w);
            a.x = fmaf(pA[b].y, w[1].x, a.x); a.y = fmaf(pA[b].y, w[1].y, a.y);
            a.z = fmaf(pA[b].y, w[1].z, a.z); a.w = fmaf(pA[b].y, w[1].w, a.w);
            a.x = fmaf(pA[b].z, w[2].x, a.x); a.y = fmaf(pA[b].z, w[2].y, a.y);
            a.z = fmaf(pA[b].z, w[2].z, a.z); a.w = fmaf(pA[b].z, w[2].w, a.w);
            a.x = fmaf(pA[b].w, w[3].x, a.x); a.y = fmaf(pA[b].w, w[3].y, a.y);
            a.z = fmaf(pA[b].w, w[3].z, a.z); a.w = fmaf(pA[b].w, w[3].w, a.w);
            a.x = fmaf(pB[b].x, w[4].x, a.x); a.y = fmaf(pB[b].x, w[4].y, a.y);
            a.z = fmaf(pB[b].x, w[4].z, a.z); a.w = fmaf(pB[b].x, w[4].w, a.w);
            a.x = fmaf(pB[b].y, w[5].x, a.x); a.y = fmaf(pB[b].y, w[5].y, a.y);
            a.z = fmaf(pB[b].y, w[5].z, a.z); a.w = fmaf(pB[b].y, w[5].w, a.w);
            a.x = fmaf(pB[b].z, w[6].x, a.x); a.y = fmaf(pB[b].z, w[6].y, a.y);
            a.z = fmaf(pB[b].z, w[6].z, a.z); a.w = fmaf(pB[b].z, w[6].w, a.w);
            a.x = fmaf(pB[b].w, w[7].x, a.x); a.y = fmaf(pB[b].w, w[7].y, a.y);
            a.z = fmaf(pB[b].w, w[7].z, a.z); a.w = fmaf(pB[b].w, w[7].w, a.w);
            acc[b] = a;
        }
    }

    float* pslice = part + (size_t)blockIdx.y * (Bdim * Ndim);
#pragma unroll
    for (int b = 0; b < Bdim; ++b)
        *reinterpret_cast<float4*>(pslice + (size_t)b * Ndim + col) = acc[b];
}

__global__ __launch_bounds__(256, 4) void snn_stage2(
    const float* __restrict__ part,  // [KCH, B*N]
    const float* __restrict__ thr,   // [B, N]
    const float* __restrict__ cst,   // [B, N]
    float* __restrict__ out)         // [B, N]
{
    const int i = blockIdx.x * 256 + threadIdx.x;   // 0 .. B*N-1
    float s = 0.f;
#pragma unroll
    for (int k = 0; k < KCH; ++k)
        s += part[(size_t)k * (Bdim * Ndim) + i];
    float x = s + cst[i] - thr[i];
    x = fminf(fmaxf(x, 0.f), CAP);
    out[i] = x;
}

extern "C" void kernel_launch(void* const* d_in, const int* in_sizes, int n_in,
                              void* d_out, int out_size, void* d_ws, size_t ws_size,
                              hipStream_t stream) {
    const float* pre = (const float*)d_in[0];   // [8,1,8192]
    const float* W   = (const float*)d_in[1];   // [8192,8192]
    const float* thr = (const float*)d_in[2];   // [8,1,8192]
    const float* cst = (const float*)d_in[3];   // [8,1,8192]
    float* out  = (float*)d_out;                // [8,1,8192]
    float* part = (float*)d_ws;                 // 16 MB partials (ws >= 16 MB)

    dim3 g1(Ndim / TILE_N, KCH);                // (8, 64)
    hipLaunchKernelGGL(snn_stage1, g1, dim3(256), 0, stream, pre, W, part);

    dim3 g2((Bdim * Ndim) / 256);               // 256
    hipLaunchKernelGGL(snn_stage2, g2, dim3(256), 0, stream, part, thr, cst, out);
}

// Round 3
// 368.108 us; speedup vs baseline: 1.1097x; 1.0296x over previous
//
#include <hip/hip_runtime.h>

// SNN layer: out[b,n] = clip( sum_m pre[b,m]*W[m,n] + cst[b,n] - thr[b,n], 0, 0.9 )
// B=8, M=8192, N=8192 fp32. Memory-bound: one pass over W = 268 MB (~43us @6.3TB/s).
//
// R3: discriminate DRAM-pattern throttling vs harness-overhead-dominated timing.
//  Stage 1: grid (4 col-panels x 128 K-chunks) = 512 blocks, 256 thr (8 waves/CU).
//    Block tile = 2048 cols x 64 rows -> 8 KB contiguous per row visit.
//    Per-block PHASE STAGGER of the row walk breaks power-of-2 lockstep
//    aliasing across the 128 concurrent 2MB-strided streams.
//    pre staged in LDS once per block -> hot loop has only W loads.
//  Stage 2: 128-way partial sum (k-order staggered per block) + fused epilogue.

constexpr int Mdim = 8192;
constexpr int Ndim = 8192;
constexpr int Bdim = 8;
constexpr int PANELS  = 4;                  // col panels
constexpr int PANEL_N = Ndim / PANELS;      // 2048 cols
constexpr int CHUNKS  = 128;                // K chunks
constexpr int CROWS   = Mdim / CHUNKS;      // 64 rows per chunk
constexpr float CAP = 0.9f;

__global__ __launch_bounds__(256, 2) void snn_stage1(
    const float* __restrict__ pre,   // [B, M]
    const float* __restrict__ W,     // [M, N]
    float* __restrict__ part)        // [CHUNKS, B, N]
{
    __shared__ float lds_pre[Bdim * CROWS];   // [b][row] 2 KB

    const int t     = threadIdx.x;
    const int panel = blockIdx.x;
    const int chunk = blockIdx.y;
    const int r0    = chunk * CROWS;
    const int colA  = panel * PANEL_N + t * 4;
    const int colB  = colA + 1024;

    // stage pre slice for this chunk: [8 batches][64 rows]
    for (int q = t; q < Bdim * CROWS; q += 256) {
        int b = q >> 6, j = q & 63;
        lds_pre[q] = pre[b * Mdim + r0 + j];
    }
    __syncthreads();

    float4 accA[Bdim], accB[Bdim];
#pragma unroll
    for (int b = 0; b < Bdim; ++b) {
        accA[b] = make_float4(0.f, 0.f, 0.f, 0.f);
        accB[b] = make_float4(0.f, 0.f, 0.f, 0.f);
    }

    // 16 iterations x 4 rows, phase-staggered start to decorrelate the
    // 128 concurrent power-of-2-strided streams at the DRAM.
    const int phase = (blockIdx.y * 5 + blockIdx.x) & 15;
    for (int i = 0; i < 16; ++i) {
        const int rr = ((i + phase) & 15) * 4;       // row offset in chunk
        const int r  = r0 + rr;

        float4 wA[4], wB[4];
#pragma unroll
        for (int j = 0; j < 4; ++j) {
            const float* row = W + (size_t)(r + j) * Ndim;
            wA[j] = *reinterpret_cast<const float4*>(row + colA);
            wB[j] = *reinterpret_cast<const float4*>(row + colB);
        }

        float4 pf[Bdim];
#pragma unroll
        for (int b = 0; b < Bdim; ++b)
            pf[b] = *reinterpret_cast<const float4*>(lds_pre + b * CROWS + rr);

#pragma unroll
        for (int b = 0; b < Bdim; ++b) {
            float4 a = accA[b], c = accB[b];
            a.x = fmaf(pf[b].x, wA[0].x, a.x); a.y = fmaf(pf[b].x, wA[0].y, a.y);
            a.z = fmaf(pf[b].x, wA[0].z, a.z); a.w = fmaf(pf[b].x, wA[0].w, a.w);
            c.x = fmaf(pf[b].x, wB[0].x, c.x); c.y = fmaf(pf[b].x, wB[0].y, c.y);
            c.z = fmaf(pf[b].x, wB[0].z, c.z); c.w = fmaf(pf[b].x, wB[0].w, c.w);

            a.x = fmaf(pf[b].y, wA[1].x, a.x); a.y = fmaf(pf[b].y, wA[1].y, a.y);
            a.z = fmaf(pf[b].y, wA[1].z, a.z); a.w = fmaf(pf[b].y, wA[1].w, a.w);
            c.x = fmaf(pf[b].y, wB[1].x, c.x); c.y = fmaf(pf[b].y, wB[1].y, c.y);
            c.z = fmaf(pf[b].y, wB[1].z, c.z); c.w = fmaf(pf[b].y, wB[1].w, c.w);

            a.x = fmaf(pf[b].z, wA[2].x, a.x); a.y = fmaf(pf[b].z, wA[2].y, a.y);
            a.z = fmaf(pf[b].z, wA[2].z, a.z); a.w = fmaf(pf[b].z, wA[2].w, a.w);
            c.x = fmaf(pf[b].z, wB[2].x, c.x); c.y = fmaf(pf[b].z, wB[2].y, c.y);
            c.z = fmaf(pf[b].z, wB[2].z, c.z); c.w = fmaf(pf[b].z, wB[2].w, c.w);

            a.x = fmaf(pf[b].w, wA[3].x, a.x); a.y = fmaf(pf[b].w, wA[3].y, a.y);
            a.z = fmaf(pf[b].w, wA[3].z, a.z); a.w = fmaf(pf[b].w, wA[3].w, a.w);
            c.x = fmaf(pf[b].w, wB[3].x, c.x); c.y = fmaf(pf[b].w, wB[3].y, c.y);
            c.z = fmaf(pf[b].w, wB[3].z, c.z); c.w = fmaf(pf[b].w, wB[3].w, c.w);
            accA[b] = a; accB[b] = c;
        }
    }

    float* ps = part + (size_t)chunk * (Bdim * Ndim);
#pragma unroll
    for (int b = 0; b < Bdim; ++b) {
        *reinterpret_cast<float4*>(ps + (size_t)b * Ndim + colA) = accA[b];
        *reinterpret_cast<float4*>(ps + (size_t)b * Ndim + colB) = accB[b];
    }
}

__global__ __launch_bounds__(256, 4) void snn_stage2(
    const float* __restrict__ part,  // [CHUNKS, B*N]
    const float* __restrict__ thr,   // [B, N]
    const float* __restrict__ cst,   // [B, N]
    float* __restrict__ out)         // [B, N]
{
    const int bid = blockIdx.x;
    const int i = bid * 256 + threadIdx.x;   // 0 .. B*N-1
    float s = 0.f;
#pragma unroll 8
    for (int k = 0; k < CHUNKS; ++k) {
        int kk = (k + bid) & (CHUNKS - 1);   // stagger streams across blocks
        s += part[(size_t)kk * (Bdim * Ndim) + i];
    }
    float x = s + cst[i] - thr[i];
    x = fminf(fmaxf(x, 0.f), CAP);
    out[i] = x;
}

extern "C" void kernel_launch(void* const* d_in, const int* in_sizes, int n_in,
                              void* d_out, int out_size, void* d_ws, size_t ws_size,
                              hipStream_t stream) {
    const float* pre = (const float*)d_in[0];   // [8,1,8192]
    const float* W   = (const float*)d_in[1];   // [8192,8192]
    const float* thr = (const float*)d_in[2];   // [8,1,8192]
    const float* cst = (const float*)d_in[3];   // [8,1,8192]
    float* out  = (float*)d_out;                // [8,1,8192]
    float* part = (float*)d_ws;                 // 32 MB partials

    dim3 g1(PANELS, CHUNKS);                    // (4, 128) = 512 blocks
    hipLaunchKernelGGL(snn_stage1, g1, dim3(256), 0, stream, pre, W, part);

    dim3 g2((Bdim * Ndim) / 256);               // 256 blocks
    hipLaunchKernelGGL(snn_stage2, g2, dim3(256), 0, stream, part, thr, cst, out);
}

// Round 4
// 361.965 us; speedup vs baseline: 1.1285x; 1.0170x over previous
//
#include <hip/hip_runtime.h>

// SNN layer: out[b,n] = clip( sum_m pre[b,m]*W[m,n] + cst[b,n] - thr[b,n], 0, 0.9 )
// B=8, M=8192, N=8192 fp32. Memory-bound: one pass over W = 268 MB (~43us @6.3TB/s).
//
// R4: software-pipelined stage1 (double-buffered W regs -> 16 KB/wave in flight)
//     + halved partial traffic (CHUNKS 128->64).
//  Stage 1: grid (8 panels x 64 K-chunks) = 512 blocks (2/CU, 8 waves/CU), 256 thr.
//    Block tile = 1024 cols x 128 rows; per-row visit 4 KB contiguous.
//    Phase-staggered row walk; pre in LDS; manual 2-deep load pipeline.
//  Stage 2: 64-way partial sum (k-order staggered) + fused epilogue.

constexpr int Mdim = 8192;
constexpr int Ndim = 8192;
constexpr int Bdim = 8;
constexpr int PANELS  = 8;                  // col panels
constexpr int PANEL_N = Ndim / PANELS;      // 1024 cols
constexpr int CHUNKS  = 64;                 // K chunks
constexpr int CROWS   = Mdim / CHUNKS;      // 128 rows per chunk
constexpr float CAP = 0.9f;

__global__ __launch_bounds__(256, 2) void snn_stage1(
    const float* __restrict__ pre,   // [B, M]
    const float* __restrict__ W,     // [M, N]
    float* __restrict__ part)        // [CHUNKS, B, N]
{
    __shared__ float lds_pre[Bdim * CROWS];   // [b][row] 4 KB

    const int t     = threadIdx.x;
    const int panel = blockIdx.x;
    const int chunk = blockIdx.y;
    const int r0    = chunk * CROWS;
    const int col   = panel * PANEL_N + t * 4;

    // stage pre slice for this chunk: [8 batches][128 rows]
#pragma unroll
    for (int q = t; q < Bdim * CROWS; q += 256) {
        int b = q >> 7, j = q & 127;
        lds_pre[q] = pre[b * Mdim + r0 + j];
    }

    float4 acc[Bdim];
#pragma unroll
    for (int b = 0; b < Bdim; ++b) acc[b] = make_float4(0.f, 0.f, 0.f, 0.f);

    const float* wcol = W + col;
    const int phase = (chunk * 5 + panel * 11) & 15;
    auto rowoff = [&](int i) { return ((i + phase) & 15) * 8; };   // 16 groups of 8 rows

    auto loadW = [&](float4* w, int rr) {
        const float* base = wcol + (size_t)(r0 + rr) * Ndim;
#pragma unroll
        for (int j = 0; j < 8; ++j)
            w[j] = *reinterpret_cast<const float4*>(base + (size_t)j * Ndim);
    };

    auto compute = [&](const float4* w, int rr) {
#pragma unroll
        for (int half = 0; half < 2; ++half) {
            const float4 w0 = w[4 * half], w1 = w[4 * half + 1],
                         w2 = w[4 * half + 2], w3 = w[4 * half + 3];
#pragma unroll
            for (int b = 0; b < Bdim; ++b) {
                float4 p = *reinterpret_cast<const float4*>(
                    lds_pre + b * CROWS + rr + 4 * half);
                float4 a = acc[b];
                a.x = fmaf(p.x, w0.x, a.x); a.y = fmaf(p.x, w0.y, a.y);
                a.z = fmaf(p.x, w0.z, a.z); a.w = fmaf(p.x, w0.w, a.w);
                a.x = fmaf(p.y, w1.x, a.x); a.y = fmaf(p.y, w1.y, a.y);
                a.z = fmaf(p.y, w1.z, a.z); a.w = fmaf(p.y, w1.w, a.w);
                a.x = fmaf(p.z, w2.x, a.x); a.y = fmaf(p.z, w2.y, a.y);
                a.z = fmaf(p.z, w2.z, a.z); a.w = fmaf(p.z, w2.w, a.w);
                a.x = fmaf(p.w, w3.x, a.x); a.y = fmaf(p.w, w3.y, a.y);
                a.z = fmaf(p.w, w3.z, a.z); a.w = fmaf(p.w, w3.w, a.w);
                acc[b] = a;
            }
        }
    };

    // 2-deep software pipeline over 16 row-groups: while computing group i,
    // group i+1's 8 KB (per wave) is in flight -> ~16 KB outstanding/wave.
    float4 wa[8], wb[8];
    loadW(wa, rowoff(0));        // issued before the barrier (no LDS dep)
    __syncthreads();

#pragma unroll
    for (int ii = 0; ii < 8; ++ii) {
        loadW(wb, rowoff(2 * ii + 1));
        compute(wa, rowoff(2 * ii));
        if (ii < 7) loadW(wa, rowoff(2 * ii + 2));
        compute(wb, rowoff(2 * ii + 1));
    }

    float* ps = part + (size_t)chunk * (Bdim * Ndim);
#pragma unroll
    for (int b = 0; b < Bdim; ++b)
        *reinterpret_cast<float4*>(ps + (size_t)b * Ndim + col) = acc[b];
}

__global__ __launch_bounds__(256, 4) void snn_stage2(
    const float* __restrict__ part,  // [CHUNKS, B*N]
    const float* __restrict__ thr,   // [B, N]
    const float* __restrict__ cst,   // [B, N]
    float* __restrict__ out)         // [B, N]
{
    const int bid = blockIdx.x;
    const int i = bid * 256 + threadIdx.x;   // 0 .. B*N-1
    float s = 0.f;
#pragma unroll 8
    for (int k = 0; k < CHUNKS; ++k) {
        int kk = (k + bid * 7) & (CHUNKS - 1);   // stagger streams across blocks
        s += part[(size_t)kk * (Bdim * Ndim) + i];
    }
    float x = s + cst[i] - thr[i];
    x = fminf(fmaxf(x, 0.f), CAP);
    out[i] = x;
}

extern "C" void kernel_launch(void* const* d_in, const int* in_sizes, int n_in,
                              void* d_out, int out_size, void* d_ws, size_t ws_size,
                              hipStream_t stream) {
    const float* pre = (const float*)d_in[0];   // [8,1,8192]
    const float* W   = (const float*)d_in[1];   // [8192,8192]
    const float* thr = (const float*)d_in[2];   // [8,1,8192]
    const float* cst = (const float*)d_in[3];   // [8,1,8192]
    float* out  = (float*)d_out;                // [8,1,8192]
    float* part = (float*)d_ws;                 // 16.8 MB partials

    dim3 g1(PANELS, CHUNKS);                    // (8, 64) = 512 blocks
    hipLaunchKernelGGL(snn_stage1, g1, dim3(256), 0, stream, pre, W, part);

    dim3 g2((Bdim * Ndim) / 256);               // 256 blocks
    hipLaunchKernelGGL(snn_stage2, g2, dim3(256), 0, stream, part, thr, cst, out);
}